// Round 9
// baseline (196.603 us; speedup 1.0000x reference)
//
#include <hip/hip_runtime.h>
#include <hip/hip_cooperative_groups.h>
#include <stdint.h>

#define BATCH 16384
#define KDIM  512
#define NDIM  1024
#define NW    16            // 512 bits = 16 uint32 words per row
#define THREADS 512         // 8 waves; each thread owns 2 adjacent columns

// coop geometry: 512 blocks (>=2/CU co-resident needed)
#define RPB_C 32
#define NPH_C (RPB_C / 4)
// fallback geometry (R4-verified): 1024 blocks
#define RPB_F 16
#define NPH_F (RPB_F / 4)

typedef int i32x2 __attribute__((ext_vector_type(2)));

// ---------- shared inner loop: fused ballot-pack(x) + GF(2) GEMM ----------
// Verified structure (rounds 3-7, absmax 0). Thread owns cols {2tid, 2tid+1}.
// Per phase: one float4/thread covers 4 rows; wave w (q=w>>1, h=w&1) ballots
// its 256 floats of row q; lane 0 deposits 8 words to LDS (double-buffered).
// Bit mapping: bit c of word (m,n) is G[kbase(m)+4c, n],
//   kbase = 256*(m>>3) + 128*((m>>2)&1) + (m&3).
template <int NPHASE>
__device__ __forceinline__
void fused_body(const float* __restrict__ x, const uint32_t* __restrict__ Gt,
                int* __restrict__ out, int row0, float4 f) {
    const int tid = threadIdx.x;
    const int w   = tid >> 6;
    const int l   = tid & 63;
    const int q   = w >> 1;
    const int h   = w & 1;

    uint32_t g0[NW], g1[NW];
#pragma unroll
    for (int m = 0; m < NW; ++m) {
        uint2 gg = reinterpret_cast<const uint2*>(Gt + m * NDIM)[tid];
        g0[m] = gg.x;
        g1[m] = gg.y;
    }

    __shared__ __align__(16) uint32_t xw[2][4][NW];   // 2 x 256 B
    const float4* xf = reinterpret_cast<const float4*>(x);

    for (int p = 0; p < NPHASE; ++p) {
        uint64_t b0 = __ballot(f.x > 0.5f);
        uint64_t b1 = __ballot(f.y > 0.5f);
        uint64_t b2 = __ballot(f.z > 0.5f);
        uint64_t b3 = __ballot(f.w > 0.5f);

        if (p + 1 < NPHASE)
            f = xf[(size_t)(row0 + (p + 1) * 4) * (KDIM / 4) + tid];

        if (l == 0) {
            uint32_t* dst = &xw[p & 1][q][h * 8];
            dst[0] = (uint32_t)b0;  dst[4] = (uint32_t)(b0 >> 32);
            dst[1] = (uint32_t)b1;  dst[5] = (uint32_t)(b1 >> 32);
            dst[2] = (uint32_t)b2;  dst[6] = (uint32_t)(b2 >> 32);
            dst[3] = (uint32_t)b3;  dst[7] = (uint32_t)(b3 >> 32);
        }
        __syncthreads();

        size_t obase = (size_t)(row0 + p * 4) * NDIM + 2 * (size_t)tid;
#pragma unroll
        for (int r = 0; r < 4; ++r) {
            const uint4* x4 = reinterpret_cast<const uint4*>(&xw[p & 1][r][0]);
            uint4 a0 = x4[0], a1 = x4[1], a2 = x4[2], a3 = x4[3];
            uint32_t t0 = (a0.x & g0[0])  ^ (a0.y & g0[1])  ^ (a0.z & g0[2])  ^ (a0.w & g0[3])
                        ^ (a1.x & g0[4])  ^ (a1.y & g0[5])  ^ (a1.z & g0[6])  ^ (a1.w & g0[7])
                        ^ (a2.x & g0[8])  ^ (a2.y & g0[9])  ^ (a2.z & g0[10]) ^ (a2.w & g0[11])
                        ^ (a3.x & g0[12]) ^ (a3.y & g0[13]) ^ (a3.z & g0[14]) ^ (a3.w & g0[15]);
            uint32_t t1 = (a0.x & g1[0])  ^ (a0.y & g1[1])  ^ (a0.z & g1[2])  ^ (a0.w & g1[3])
                        ^ (a1.x & g1[4])  ^ (a1.y & g1[5])  ^ (a1.z & g1[6])  ^ (a1.w & g1[7])
                        ^ (a2.x & g1[8])  ^ (a2.y & g1[9])  ^ (a2.z & g1[10]) ^ (a2.w & g1[11])
                        ^ (a3.x & g1[12]) ^ (a3.y & g1[13]) ^ (a3.z & g1[14]) ^ (a3.w & g1[15]);
            i32x2 o;
            o.x = (int)(__popc(t0) & 1u);
            o.y = (int)(__popc(t1) & 1u);
            *reinterpret_cast<i32x2*>(out + obase + (size_t)r * NDIM) = o;
        }
    }
}

// ---------- cooperative single-dispatch version ----------
__global__ __launch_bounds__(THREADS, 4)
void gf2_onekernel(const float* __restrict__ x,
                   const float* __restrict__ G,
                   uint32_t* __restrict__ Gt,
                   int* __restrict__ out) {
    const int tid = threadIdx.x;
    const int bid = blockIdx.x;
    const int row0 = bid * RPB_C;

    // early x prefetch for phase 0 (HBM latency hides under pack+sync)
    const float4* xf = reinterpret_cast<const float4*>(x);
    float4 f = xf[(size_t)row0 * (KDIM / 4) + tid];

    // pack this block's Gt slice: word m = bid>>5, cols (bid&31)*32..+31
    {
        __shared__ uint32_t nib[16][32];
        const int m  = bid >> 5;
        const int n0 = (bid & 31) << 5;
        const int p  = tid >> 5;             // piece 0..15 (bits 2p, 2p+1)
        const int nn = tid & 31;
        const int kbase = 256 * (m >> 3) + 128 * ((m >> 2) & 1) + (m & 3);
        uint32_t w = 0;
#pragma unroll
        for (int j = 0; j < 2; ++j) {
            int c = 2 * p + j;
            w |= (uint32_t)(G[(size_t)(kbase + 4 * c) * NDIM + n0 + nn] > 0.5f) << c;
        }
        nib[p][nn] = w;
        __syncthreads();
        if (tid < 32) {
            uint32_t r = nib[0][tid]  | nib[1][tid]  | nib[2][tid]  | nib[3][tid]
                       | nib[4][tid]  | nib[5][tid]  | nib[6][tid]  | nib[7][tid]
                       | nib[8][tid]  | nib[9][tid]  | nib[10][tid] | nib[11][tid]
                       | nib[12][tid] | nib[13][tid] | nib[14][tid] | nib[15][tid];
            Gt[m * NDIM + n0 + tid] = r;
        }
    }
    __threadfence();                          // release: Gt stores device-visible
    cooperative_groups::this_grid().sync();
    __threadfence();                          // acquire: invalidate stale caches

    fused_body<NPH_C>(x, Gt, out, row0, f);
}

// ---------- fallback kernels (R4/R5-verified two-dispatch path) ----------
__global__ __launch_bounds__(256) void pack_g_kernel(const float* __restrict__ G,
                                                     uint32_t* __restrict__ Gt) {
    __shared__ uint32_t nib[8][32];
    const int bid = blockIdx.x;          // 512 blocks
    const int m   = bid >> 5;
    const int n0  = (bid & 31) << 5;
    const int tid = threadIdx.x;
    const int p   = tid >> 5;            // piece 0..7 (bits 4p..4p+3)
    const int nn  = tid & 31;
    const int kbase = 256 * (m >> 3) + 128 * ((m >> 2) & 1) + (m & 3);
    uint32_t w = 0;
#pragma unroll
    for (int j = 0; j < 4; ++j) {
        int c = 4 * p + j;
        w |= (uint32_t)(G[(size_t)(kbase + 4 * c) * NDIM + n0 + nn] > 0.5f) << c;
    }
    nib[p][nn] = w;
    __syncthreads();
    if (tid < 32) {
        uint32_t r = nib[0][tid] | nib[1][tid] | nib[2][tid] | nib[3][tid]
                   | nib[4][tid] | nib[5][tid] | nib[6][tid] | nib[7][tid];
        Gt[m * NDIM + n0 + tid] = r;
    }
}

__global__ __launch_bounds__(THREADS, 6)
void gf2_fused_kernel(const float* __restrict__ x,
                      const uint32_t* __restrict__ Gt,
                      int* __restrict__ out) {
    const int row0 = blockIdx.x * RPB_F;
    const float4* xf = reinterpret_cast<const float4*>(x);
    float4 f = xf[(size_t)row0 * (KDIM / 4) + threadIdx.x];
    fused_body<NPH_F>(x, Gt, out, row0, f);
}

extern "C" void kernel_launch(void* const* d_in, const int* in_sizes, int n_in,
                              void* d_out, int out_size, void* d_ws, size_t ws_size,
                              hipStream_t stream) {
    const float* x = (const float*)d_in[0];   // [BATCH, KDIM] float32 (0/1)
    const float* G = (const float*)d_in[1];   // [KDIM, NDIM] float32 (0/1)
    int* out = (int*)d_out;                   // [BATCH, NDIM] int32
    uint32_t* Gt = (uint32_t*)d_ws;           // 64 KiB packed G

    void* args[] = { (void*)&x, (void*)&G, (void*)&Gt, (void*)&out };
    hipError_t e = hipLaunchCooperativeKernel((const void*)gf2_onekernel,
                                              dim3(BATCH / RPB_C), dim3(THREADS),
                                              args, 0, stream);
    if (e != hipSuccess) {
        (void)hipGetLastError();   // clear sticky error, use verified 2-kernel path
        pack_g_kernel<<<512, 256, 0, stream>>>(G, Gt);
        gf2_fused_kernel<<<BATCH / RPB_F, THREADS, 0, stream>>>(x, Gt, out);
    }
}

// Round 10
// 28.741 us; speedup vs baseline: 6.8405x; 6.8405x over previous
//
#include <hip/hip_runtime.h>
#include <stdint.h>

#define BATCH 16384
#define KDIM  512
#define NDIM  1024
#define NW    16            // 512 bits = 16 uint32 words per row
#define THREADS 256         // 4 waves; each thread owns 4 adjacent columns
#define ROWS_PER_BLOCK 16   // 1024 blocks (4/CU co-resident)
#define PHASE_ROWS 2        // one float4/thread = 2 rows per phase
#define NPHASE (ROWS_PER_BLOCK / PHASE_ROWS)

typedef int i32x4 __attribute__((ext_vector_type(4)));

// --- G packing (UNCHANGED — verified rounds 2-7): 512 blocks, 8 threads
// per word (4 bits each), LDS combine. Bit c of word (m,n) is
// G[kbase(m) + 4c, n], kbase = 256*(m>>3) + 128*((m>>2)&1) + (m&3).
__global__ __launch_bounds__(256) void pack_g_kernel(const float* __restrict__ G,
                                                     uint32_t* __restrict__ Gt) {
    __shared__ uint32_t nib[8][32];
    const int bid = blockIdx.x;          // 512 blocks
    const int m   = bid >> 5;            // 0..15
    const int n0  = (bid & 31) << 5;     // column chunk base
    const int tid = threadIdx.x;
    const int p   = tid >> 5;            // piece 0..7 (bits 4p..4p+3)
    const int nn  = tid & 31;
    const int kbase = 256 * (m >> 3) + 128 * ((m >> 2) & 1) + (m & 3);
    uint32_t w = 0;
#pragma unroll
    for (int j = 0; j < 4; ++j) {
        int c = 4 * p + j;
        w |= (uint32_t)(G[(size_t)(kbase + 4 * c) * NDIM + n0 + nn] > 0.5f) << c;
    }
    nib[p][nn] = w;
    __syncthreads();
    if (tid < 32) {
        uint32_t r = nib[0][tid] | nib[1][tid] | nib[2][tid] | nib[3][tid]
                   | nib[4][tid] | nib[5][tid] | nib[6][tid] | nib[7][tid];
        Gt[m * NDIM + n0 + tid] = r;
    }
}

// --- fused pack(x) + GF(2) GEMM, 4 columns/thread, int4 stores ---
// 256 threads (4 waves). Thread owns cols {4tid..4tid+3}: g[4][16] = 64 VGPRs.
// Per phase: one float4/thread covers 2 rows (e = 4*tid + j; row = e>>9;
// k = e&511 = 256*(w&1) + 4*lane + j -> SAME kbase mapping as pack_g).
// Wave w (q = w>>1, h = w&1) ballots row q; lane 0 deposits 8 words to LDS
// (double-buffered, one barrier per phase). Each row's 4 ds_read_b128 now
// feed 4 output columns (1 LDS read per output), stores are 16 B/lane int4.
__global__ __launch_bounds__(THREADS, 4)
void gf2_fused_kernel(const float* __restrict__ x,
                      const uint32_t* __restrict__ Gt,
                      int* __restrict__ out) {
    const int tid = threadIdx.x;
    const int w   = tid >> 6;     // wave 0..3
    const int l   = tid & 63;     // lane
    const int q   = w >> 1;       // row within phase (0..1)
    const int h   = w & 1;        // k-half (0: k<256, 1: k>=256)
    const int row0 = blockIdx.x * ROWS_PER_BLOCK;

    // persistent column fragments: cols 4tid..4tid+3 (coalesced uint4 loads)
    uint32_t g0[NW], g1[NW], g2[NW], g3[NW];
#pragma unroll
    for (int m = 0; m < NW; ++m) {
        uint4 gg = reinterpret_cast<const uint4*>(Gt + m * NDIM)[tid];
        g0[m] = gg.x;
        g1[m] = gg.y;
        g2[m] = gg.z;
        g3[m] = gg.w;
    }

    __shared__ __align__(16) uint32_t xw[2][PHASE_ROWS][NW];   // 2 x 128 B

    const float4* xf = reinterpret_cast<const float4*>(x);
    float4 f = xf[(size_t)row0 * (KDIM / 4) + tid];            // phase-0 slab

    for (int p = 0; p < NPHASE; ++p) {
        // ---- ballot-pack 2 rows (consumes f) ----
        uint64_t b0 = __ballot(f.x > 0.5f);
        uint64_t b1 = __ballot(f.y > 0.5f);
        uint64_t b2 = __ballot(f.z > 0.5f);
        uint64_t b3 = __ballot(f.w > 0.5f);

        // prefetch next phase's slab (hidden under compute below)
        if (p + 1 < NPHASE)
            f = xf[(size_t)(row0 + (p + 1) * PHASE_ROWS) * (KDIM / 4) + tid];

        if (l == 0) {
            uint32_t* dst = &xw[p & 1][q][h * 8];
            dst[0] = (uint32_t)b0;  dst[4] = (uint32_t)(b0 >> 32);
            dst[1] = (uint32_t)b1;  dst[5] = (uint32_t)(b1 >> 32);
            dst[2] = (uint32_t)b2;  dst[6] = (uint32_t)(b2 >> 32);
            dst[3] = (uint32_t)b3;  dst[7] = (uint32_t)(b3 >> 32);
        }
        __syncthreads();   // double-buffer: one barrier per phase is race-free

        // ---- compute 2 rows x 4 columns ----
        size_t obase = (size_t)(row0 + p * PHASE_ROWS) * NDIM + 4 * (size_t)tid;
#pragma unroll
        for (int r = 0; r < PHASE_ROWS; ++r) {
            const uint4* x4 = reinterpret_cast<const uint4*>(&xw[p & 1][r][0]);
            uint4 a0 = x4[0], a1 = x4[1], a2 = x4[2], a3 = x4[3];
            uint32_t t0 = (a0.x & g0[0])  ^ (a0.y & g0[1])  ^ (a0.z & g0[2])  ^ (a0.w & g0[3])
                        ^ (a1.x & g0[4])  ^ (a1.y & g0[5])  ^ (a1.z & g0[6])  ^ (a1.w & g0[7])
                        ^ (a2.x & g0[8])  ^ (a2.y & g0[9])  ^ (a2.z & g0[10]) ^ (a2.w & g0[11])
                        ^ (a3.x & g0[12]) ^ (a3.y & g0[13]) ^ (a3.z & g0[14]) ^ (a3.w & g0[15]);
            uint32_t t1 = (a0.x & g1[0])  ^ (a0.y & g1[1])  ^ (a0.z & g1[2])  ^ (a0.w & g1[3])
                        ^ (a1.x & g1[4])  ^ (a1.y & g1[5])  ^ (a1.z & g1[6])  ^ (a1.w & g1[7])
                        ^ (a2.x & g1[8])  ^ (a2.y & g1[9])  ^ (a2.z & g1[10]) ^ (a2.w & g1[11])
                        ^ (a3.x & g1[12]) ^ (a3.y & g1[13]) ^ (a3.z & g1[14]) ^ (a3.w & g1[15]);
            uint32_t t2 = (a0.x & g2[0])  ^ (a0.y & g2[1])  ^ (a0.z & g2[2])  ^ (a0.w & g2[3])
                        ^ (a1.x & g2[4])  ^ (a1.y & g2[5])  ^ (a1.z & g2[6])  ^ (a1.w & g2[7])
                        ^ (a2.x & g2[8])  ^ (a2.y & g2[9])  ^ (a2.z & g2[10]) ^ (a2.w & g2[11])
                        ^ (a3.x & g2[12]) ^ (a3.y & g2[13]) ^ (a3.z & g2[14]) ^ (a3.w & g2[15]);
            uint32_t t3 = (a0.x & g3[0])  ^ (a0.y & g3[1])  ^ (a0.z & g3[2])  ^ (a0.w & g3[3])
                        ^ (a1.x & g3[4])  ^ (a1.y & g3[5])  ^ (a1.z & g3[6])  ^ (a1.w & g3[7])
                        ^ (a2.x & g3[8])  ^ (a2.y & g3[9])  ^ (a2.z & g3[10]) ^ (a2.w & g3[11])
                        ^ (a3.x & g3[12]) ^ (a3.y & g3[13]) ^ (a3.z & g3[14]) ^ (a3.w & g3[15]);
            i32x4 o;
            o.x = (int)(__popc(t0) & 1u);
            o.y = (int)(__popc(t1) & 1u);
            o.z = (int)(__popc(t2) & 1u);
            o.w = (int)(__popc(t3) & 1u);
            *reinterpret_cast<i32x4*>(out + obase + (size_t)r * NDIM) = o;
        }
    }
}

extern "C" void kernel_launch(void* const* d_in, const int* in_sizes, int n_in,
                              void* d_out, int out_size, void* d_ws, size_t ws_size,
                              hipStream_t stream) {
    const float* x = (const float*)d_in[0];   // [BATCH, KDIM] float32 (0/1)
    const float* G = (const float*)d_in[1];   // [KDIM, NDIM] float32 (0/1)
    int* out = (int*)d_out;                   // [BATCH, NDIM] int32

    uint32_t* Gt = (uint32_t*)d_ws;           // 64 KiB packed G

    pack_g_kernel<<<512, 256, 0, stream>>>(G, Gt);
    gf2_fused_kernel<<<BATCH / ROWS_PER_BLOCK, THREADS, 0, stream>>>(x, Gt, out);
}